// Round 4
// baseline (68.726 us; speedup 1.0000x reference)
//
#include <hip/hip_runtime.h>

namespace {

constexpr int BATCH = 4, SEQ = 4096, DM = 256, DP = 80;
constexpr int NCH = 16;
constexpr float ALPHA = 0.1f;

__device__ __forceinline__ float dot4(float4 a, float4 b) {
  return a.x * b.x + a.y * b.y + a.z * b.z + a.w * b.w;
}

__device__ __forceinline__ float wave_red(float s) {
  s += __shfl_down(s, 32); s += __shfl_down(s, 16); s += __shfl_down(s, 8);
  s += __shfl_down(s, 4);  s += __shfl_down(s, 2);  s += __shfl_down(s, 1);
  return s;
}

// row (global, >=65 floats, 16B-aligned) dot v (LDS, 16B-aligned), 65 terms
__device__ __forceinline__ float rowdot65(const float* __restrict__ row,
                                          const float* v) {
  float s0 = 0.f, s1 = 0.f;
#pragma unroll
  for (int u = 0; u < 16; u += 2) {
    s0 += dot4(*reinterpret_cast<const float4*>(row + u * 4),
               *reinterpret_cast<const float4*>(v + u * 4));
    s1 += dot4(*reinterpret_cast<const float4*>(row + (u + 1) * 4),
               *reinterpret_cast<const float4*>(v + (u + 1) * 4));
  }
  return s0 + s1 + row[64] * v[64];
}

// sum_k v[k] * Mt[k*DP + i],  k<256 (Mt global [256][80]); 4 indep acc chains
__device__ __forceinline__ float coldot(const float* __restrict__ Mt,
                                        const float* v, int i) {
  float a0 = 0.f, a1 = 0.f, a2 = 0.f, a3 = 0.f;
  for (int k = 0; k < 256; k += 4) {
    a0 += v[k + 0] * Mt[(size_t)(k + 0) * DP + i];
    a1 += v[k + 1] * Mt[(size_t)(k + 1) * DP + i];
    a2 += v[k + 2] * Mt[(size_t)(k + 2) * DP + i];
    a3 += v[k + 3] * Mt[(size_t)(k + 3) * DP + i];
  }
  return (a0 + a1) + (a2 + a3);
}

// ---------------------------------------------------------------------------
// Kernel 1 (328 blocks x 256): everything except the per-batch chain.
//  [0,66):    Y1t rows  (e->Wv0->Wq1->Wk1^T; F0t side-store)  [heaviest first]
//  [66,132):  Z0t rows  (e->Wq0->Wk0^T)
//  [132,198): Z1t rows  (e->Wq1->Wk1^T)
//  [198,326): x^T x partials, (batch, chunk, col-half)
//  326:       Et build + pad-zeroing of Et/Z0t/F0t
//  327:       w1 = Wv1 @ Wout
// Row blocks: 33 groups of 2 rows x 2 col-halves per matrix.
// ---------------------------------------------------------------------------
__global__ __launch_bounds__(256)
void k_pre(const float* __restrict__ x, const float* __restrict__ Wemb,
           const float* __restrict__ bemb, const float* __restrict__ Wq,
           const float* __restrict__ Wk, const float* __restrict__ Wv,
           const float* __restrict__ Wout,
           float* __restrict__ Xp, float* __restrict__ cp,
           float* __restrict__ Z0t, float* __restrict__ Z1t,
           float* __restrict__ Y1t, float* __restrict__ F0t,
           float* __restrict__ Et, float* __restrict__ w1g) {
  const int bid = blockIdx.x, t = threadIdx.x;
  __shared__ __align__(16) float esT[512];   // [k][r] interleaved
  __shared__ __align__(16) float psT[512];
  __shared__ __align__(16) float fsT[512];
  __shared__ __align__(16) float xs[16][64];
  __shared__ __align__(16) float cs[16][64];

  if (bid < 198) {
    // ---------------- chain-row blocks ----------------
    int role, idx;
    if (bid < 66)       { role = 0; idx = bid; }        // Y1
    else if (bid < 132) { role = 1; idx = bid - 66; }   // Z0
    else                { role = 2; idx = bid - 132; }  // Z1
    const int grp = idx >> 1, half = idx & 1;
    const int r0 = grp * 2;
    const int nr = (r0 + 2 <= 65) ? 2 : 1;

    // stage 2 rows of Ebar, interleaved [k][r]
    {
      const float v0 = (r0 < 64) ? Wemb[(size_t)r0 * DM + t] : bemb[t];
      float v1 = 0.f;
      if (nr == 2) v1 = (r0 + 1 < 64) ? Wemb[(size_t)(r0 + 1) * DM + t] : bemb[t];
      esT[t * 2 + 0] = v0;
      esT[t * 2 + 1] = v1;
    }
    __syncthreads();

    const float* M1; const float* M2; float* dst;
    const float* src = esT;
    if (role == 0) {
      // f0 = e @ Wv0  -> fsT ; side-store F0t (half 0 only)
      const float* Wv0 = Wv;
      float a0 = 0.f, a1 = 0.f;
#pragma unroll 4
      for (int k = 0; k < 256; ++k) {
        const float w = Wv0[(size_t)k * DM + t];
        a0 += esT[k * 2 + 0] * w;
        a1 += esT[k * 2 + 1] * w;
      }
      fsT[t * 2 + 0] = a0;
      fsT[t * 2 + 1] = a1;
      if (half == 0) {
        F0t[(size_t)t * DP + r0] = a0;
        if (nr == 2) F0t[(size_t)t * DP + r0 + 1] = a1;
      }
      __syncthreads();
      src = fsT;
      M1 = Wq + (size_t)DM * DM;  // Wq1
      M2 = Wk + (size_t)DM * DM;  // Wk1
      dst = Y1t;
    } else if (role == 1) {
      M1 = Wq; M2 = Wk; dst = Z0t;
    } else {
      M1 = Wq + (size_t)DM * DM; M2 = Wk + (size_t)DM * DM; dst = Z1t;
    }

    // NT pass: p[r][j] = sum_k src[k][r] * M1[k][j]   (lane j = t)
    {
      float a0 = 0.f, a1 = 0.f;
#pragma unroll 4
      for (int k = 0; k < 256; ++k) {
        const float w = M1[(size_t)k * DM + t];
        a0 += src[k * 2 + 0] * w;
        a1 += src[k * 2 + 1] * w;
      }
      psT[t * 2 + 0] = a0;
      psT[t * 2 + 1] = a1;
    }
    __syncthreads();

    // TN half pass: z[r][j] = sum_k p[r][k] * M2[j][k]; store dst[j][r0+r]
    {
      const int j = half * 128 + (t & 127);
      const int r = t >> 7;  // wave-uniform
      float acc = 0.f;
#pragma unroll 2
      for (int k4 = 0; k4 < 64; ++k4) {
        const float4 m =
            *reinterpret_cast<const float4*>(M2 + (size_t)j * DM + k4 * 4);
        acc += m.x * psT[(k4 * 4 + 0) * 2 + r] + m.y * psT[(k4 * 4 + 1) * 2 + r] +
               m.z * psT[(k4 * 4 + 2) * 2 + r] + m.w * psT[(k4 * 4 + 3) * 2 + r];
      }
      if (r < nr) dst[(size_t)j * DP + r0 + r] = acc;
    }
  } else if (bid < 326) {
    // ---------------- x^T x partial blocks (col-halved) ----------------
    const int idx = bid - 198;
    const int b = idx >> 5, r5 = idx & 31, ch = r5 >> 1, half = r5 & 1;
    const float* xb = x + ((size_t)b * SEQ + (size_t)ch * 256) * 64;
    const int trs = t >> 4, tcs = t & 15;  // stage map
    const int tr2 = t >> 3, tc2 = t & 7;   // compute map (2 rows x 4 cols)

    float acc[2][4];
#pragma unroll
    for (int i = 0; i < 2; ++i)
#pragma unroll
      for (int j = 0; j < 4; ++j) acc[i][j] = 0.f;
    float4 csum = make_float4(0.f, 0.f, 0.f, 0.f);

    for (int st = 0; st < 16; ++st) {
      const float4 v = *reinterpret_cast<const float4*>(
          xb + (size_t)(st * 16 + trs) * 64 + tcs * 4);
      __syncthreads();
      *reinterpret_cast<float4*>(&xs[trs][tcs * 4]) = v;
      csum.x += v.x; csum.y += v.y; csum.z += v.z; csum.w += v.w;
      __syncthreads();
#pragma unroll
      for (int s = 0; s < 16; ++s) {
        const float a0 = xs[s][tr2 * 2 + 0];
        const float a1 = xs[s][tr2 * 2 + 1];
        const float4 b4 =
            *reinterpret_cast<const float4*>(&xs[s][half * 32 + tc2 * 4]);
        acc[0][0] += a0 * b4.x; acc[0][1] += a0 * b4.y;
        acc[0][2] += a0 * b4.z; acc[0][3] += a0 * b4.w;
        acc[1][0] += a1 * b4.x; acc[1][1] += a1 * b4.y;
        acc[1][2] += a1 * b4.z; acc[1][3] += a1 * b4.w;
      }
    }
    float* Xpb = Xp + (size_t)(b * NCH + ch) * 4096;
#pragma unroll
    for (int rr = 0; rr < 2; ++rr) {
      const float4 s4 =
          make_float4(acc[rr][0], acc[rr][1], acc[rr][2], acc[rr][3]);
      *reinterpret_cast<float4*>(
          &Xpb[(size_t)(tr2 * 2 + rr) * 64 + half * 32 + tc2 * 4]) = s4;
    }
    if (half == 0) {
      *reinterpret_cast<float4*>(&cs[trs][tcs * 4]) = csum;
      __syncthreads();
      if (t < 64) {
        float s = 0.f;
#pragma unroll
        for (int g = 0; g < 16; ++g) s += cs[g][t];
        cp[(size_t)(b * NCH + ch) * 64 + t] = s;
      }
    }
  } else if (bid == 326) {
    // ---------------- Et build + pad zeroing ----------------
    for (int i = 0; i < 64; ++i) Et[(size_t)t * DP + i] = Wemb[(size_t)i * DM + t];
    Et[(size_t)t * DP + 64] = bemb[t];
    for (int i = 65; i < DP; ++i) {
      Et[(size_t)t * DP + i] = 0.f;
      Z0t[(size_t)t * DP + i] = 0.f;  // read by 80-lane coldots -> must be finite
      F0t[(size_t)t * DP + i] = 0.f;
    }
  } else {
    // ---------------- w1 = Wv1 @ Wout ----------------
    esT[t] = Wout[t];
    __syncthreads();
    const float* Wv1 = Wv + (size_t)DM * DM;
    float a = 0.f;
    for (int k4 = 0; k4 < 64; ++k4) {
      const float4 m =
          *reinterpret_cast<const float4*>(Wv1 + (size_t)t * DM + k4 * 4);
      a += m.x * esT[k4 * 4 + 0] + m.y * esT[k4 * 4 + 1] +
           m.z * esT[k4 * 4 + 2] + m.w * esT[k4 * 4 + 3];
    }
    w1g[t] = a;
  }
}

// ---------------------------------------------------------------------------
// Kernel 2 (4 blocks x 1024): per-batch chain in 65/80-dim space.
//   out = cbar.e_o + a*(g.f0) + a*(pv.Xq) + bout
// ---------------------------------------------------------------------------
__global__ __launch_bounds__(1024)
void k_post(const float* __restrict__ Xp, const float* __restrict__ cp,
            const float* __restrict__ Et, const float* __restrict__ F0t,
            const float* __restrict__ Z0t, const float* __restrict__ Z1t,
            const float* __restrict__ Y1t, const float* __restrict__ Wout,
            const float* __restrict__ bout, const float* __restrict__ w1g,
            float* __restrict__ out) {
  const int b = blockIdx.x, t = threadIdx.x;
  __shared__ __align__(16) float X[DP][81];
  __shared__ __align__(16) float cl[DP], eo[DP], e1[DP], f0[DP], f1[DP];
  __shared__ __align__(16) float al[256], hv[256], z2[256], t2[256];
  __shared__ __align__(16) float cM0[DP], y[DP], g[DP], qv[DP];
  __shared__ __align__(16) float rE[DP], rF[DP], t1[DP], Xq[DP];
  __shared__ __align__(16) float pr0[DP], pr1[DP], pr2[DP];
  __shared__ float dots[3];

  // ---- P1: Xbar reduce / cbar / e,f vectors / pad zeroing  (parallel)
  if (t < 512) {
    const int e = t * 8;
    float4 aA = make_float4(0.f, 0.f, 0.f, 0.f);
    float4 aB = make_float4(0.f, 0.f, 0.f, 0.f);
    for (int ch = 0; ch < NCH; ++ch) {
      const float* P = Xp + (size_t)(b * NCH + ch) * 4096 + e;
      const float4 p1 = *reinterpret_cast<const float4*>(P);
      const float4 p2 = *reinterpret_cast<const float4*>(P + 4);
      aA.x += p1.x; aA.y += p1.y; aA.z += p1.z; aA.w += p1.w;
      aB.x += p2.x; aB.y += p2.y; aB.z += p2.z; aB.w += p2.w;
    }
    const int r = e >> 6, c = e & 63;
    X[r][c + 0] = aA.x; X[r][c + 1] = aA.y; X[r][c + 2] = aA.z; X[r][c + 3] = aA.w;
    X[r][c + 4] = aB.x; X[r][c + 5] = aB.y; X[r][c + 6] = aB.z; X[r][c + 7] = aB.w;
  } else if (t < 576) {
    const int i = t - 512;
    float s = 0.f;
    for (int ch = 0; ch < NCH; ++ch) s += cp[(size_t)(b * NCH + ch) * 64 + i];
    cl[i] = s;
    if (i == 0) cl[64] = (float)SEQ;
    if (i == 1) for (int p = 65; p < DP; ++p) cl[p] = 0.f;
  } else if (t < 896) {
    const int u = t - 576, grp = u / DP, i = u - grp * DP;
    const float* Mt = (grp < 2) ? Et : F0t;
    const float* v  = (grp & 1) ? w1g : Wout;
    const float r = coldot(Mt, v, i);
    if (grp == 0) eo[i] = r;
    else if (grp == 1) e1[i] = r;
    else if (grp == 2) f0[i] = r;
    else f1[i] = r;
  } else {
    for (int n = t - 896; n < 2304; n += 128) {
      if (n < 1280) X[n >> 4][64 + (n & 15)] = 0.f;
      else { const int m = n - 1280; X[64 + (m >> 6)][m & 63] = 0.f; }
    }
  }
  __syncthreads();

  // ---- P2: finish Xbar (c row/col), a = cbar @ Z0
  if (t < 64) { X[t][64] = cl[t]; X[64][t] = cl[t]; }
  else if (t == 64) X[64][64] = (float)SEQ;
  else if (t >= 128 && t < 384)
    al[t - 128] = rowdot65(Z0t + (size_t)(t - 128) * DP, cl);
  __syncthreads();

  // ---- S2: cM0 = a Ebar^T ; y = Xbar f1
  if (t < 80) cM0[t] = coldot(Et, al, t);
  else if (t >= 128 && t < 208) {
    const int i = t - 128; float s = 0.f;
    for (int j = 0; j < DP; ++j) s += X[i][j] * f1[j];
    y[i] = s;
  }
  __syncthreads();

  // ---- S3: g = cM0 Xbar ; z2 = y Ebar
  if (t < 80) {
    float s = 0.f;
    for (int i = 0; i < DP; ++i) s += cM0[i] * X[i][t];
    g[t] = s;
  } else if (t >= 128 && t < 384)
    z2[t - 128] = rowdot65(Et + (size_t)(t - 128) * DP, y);
  __syncthreads();

  // ---- S4: hv = cbar Z1 + a*(g Y1) ; qv = e1 + a*(z2 Z0^T)
  if (t < 256)
    hv[t] = rowdot65(Z1t + (size_t)t * DP, cl) +
            ALPHA * rowdot65(Y1t + (size_t)t * DP, g);
  else if (t < 336) {
    const int i = t - 256;
    qv[i] = e1[i] + ALPHA * coldot(Z0t, z2, i);
  }
  __syncthreads();

  // ---- S5: rE = hv Ebar^T ; rF = hv F0^T ; Xq = Xbar qv
  if (t < 80) rE[t] = coldot(Et, hv, t);
  else if (t >= 128 && t < 208) rF[t - 128] = coldot(F0t, hv, t - 128);
  else if (t >= 256 && t < 336) {
    const int i = t - 256; float s = 0.f;
    for (int j = 0; j < DP; ++j) s += X[i][j] * qv[j];
    Xq[i] = s;
  }
  __syncthreads();

  // ---- S6: t1 = rF Xbar
  if (t < 80) {
    float s = 0.f;
    for (int i = 0; i < DP; ++i) s += rF[i] * X[i][t];
    t1[t] = s;
  }
  __syncthreads();

  // ---- S7: t2 = t1 Ebar
  if (t < 256) t2[t] = rowdot65(Et + (size_t)t * DP, t1);
  __syncthreads();

  // ---- S8: pv = rE + a*(t2 Z0^T); products
  if (t < 80) {
    const float zv = coldot(Z0t, t2, t);
    pr2[t] = (rE[t] + ALPHA * zv) * Xq[t];
  } else if (t >= 128 && t < 208) {
    const int i = t - 128; pr0[i] = cl[i] * eo[i];
  } else if (t >= 256 && t < 336) {
    const int i = t - 256; pr1[i] = g[i] * f0[i];
  }
  __syncthreads();

  // ---- S9: reduce 3 dots
  const int w = t >> 6, l = t & 63;
  if (w < 3) {
    const float* pr = (w == 0) ? pr0 : (w == 1) ? pr1 : pr2;
    float v = pr[l] + ((l < 16) ? pr[64 + l] : 0.f);
    v = wave_red(v);
    if (l == 0) dots[w] = v;
  }
  __syncthreads();
  if (t == 0) out[b] = dots[0] + ALPHA * dots[1] + ALPHA * dots[2] + bout[0];
}

}  // namespace

extern "C" void kernel_launch(void* const* d_in, const int* in_sizes, int n_in,
                              void* d_out, int out_size, void* d_ws, size_t ws_size,
                              hipStream_t stream) {
  const float* x    = (const float*)d_in[0];
  const float* Wemb = (const float*)d_in[1];
  const float* bemb = (const float*)d_in[2];
  const float* Wq   = (const float*)d_in[3];
  const float* Wk   = (const float*)d_in[4];
  const float* Wv   = (const float*)d_in[5];
  const float* Wout = (const float*)d_in[6];
  const float* bout = (const float*)d_in[7];
  float* out = (float*)d_out;

  float* p = (float*)d_ws;
  float* Xp  = p; p += (size_t)BATCH * NCH * 4096;  // 1 MB
  float* cp  = p; p += (size_t)BATCH * NCH * 64;
  float* Z0t = p; p += 256 * DP;
  float* Z1t = p; p += 256 * DP;
  float* Y1t = p; p += 256 * DP;
  float* F0t = p; p += 256 * DP;
  float* Et  = p; p += 256 * DP;
  float* w1g = p; p += 256;

  k_pre<<<328, 256, 0, stream>>>(x, Wemb, bemb, Wq, Wk, Wv, Wout,
                                 Xp, cp, Z0t, Z1t, Y1t, F0t, Et, w1g);
  k_post<<<BATCH, 1024, 0, stream>>>(Xp, cp, Et, F0t, Z0t, Z1t, Y1t,
                                     Wout, bout, w1g, out);
}

// Round 5
// 66.504 us; speedup vs baseline: 1.0334x; 1.0334x over previous
//
#include <hip/hip_runtime.h>

namespace {

constexpr int BATCH = 4, SEQ = 4096, DM = 256, DP = 80;
constexpr float ALPHA = 0.1f;

__device__ __forceinline__ float dot4(float4 a, float4 b) {
  return a.x * b.x + a.y * b.y + a.z * b.z + a.w * b.w;
}

__device__ __forceinline__ float wave_red(float s) {
  s += __shfl_down(s, 32); s += __shfl_down(s, 16); s += __shfl_down(s, 8);
  s += __shfl_down(s, 4);  s += __shfl_down(s, 2);  s += __shfl_down(s, 1);
  return s;
}

// 65-term dot: row (global, [*][DP] rows, 16B aligned) . v (LDS)
__device__ __forceinline__ float rowdot65(const float* __restrict__ row,
                                          const float* v) {
  float s0 = 0.f, s1 = 0.f;
#pragma unroll
  for (int u = 0; u < 16; u += 2) {
    s0 += dot4(*reinterpret_cast<const float4*>(row + u * 4),
               *reinterpret_cast<const float4*>(v + u * 4));
    s1 += dot4(*reinterpret_cast<const float4*>(row + (u + 1) * 4),
               *reinterpret_cast<const float4*>(v + (u + 1) * 4));
  }
  return s0 + s1 + row[64] * v[64];
}

// 256-term contiguous dot, 16 independent loads in flight
__device__ __forceinline__ float rowdot256(const float* __restrict__ row,
                                           const float* v) {
  const float4* R = reinterpret_cast<const float4*>(row);
  const float4* V = reinterpret_cast<const float4*>(v);
  float a0 = 0.f, a1 = 0.f, a2 = 0.f, a3 = 0.f;
#pragma unroll 4
  for (int u = 0; u < 16; ++u) {
    a0 += dot4(R[u * 4 + 0], V[u * 4 + 0]);
    a1 += dot4(R[u * 4 + 1], V[u * 4 + 1]);
    a2 += dot4(R[u * 4 + 2], V[u * 4 + 2]);
    a3 += dot4(R[u * 4 + 3], V[u * 4 + 3]);
  }
  return (a0 + a1) + (a2 + a3);
}

// ---------------------------------------------------------------------------
// Kernel 1: [0,66) Y1 rows, [66,132) Z0 rows, [132,198) Z1 rows,
//           [198,198+B*nch*2) x^T x partials, then fill block, then w1 block.
// ---------------------------------------------------------------------------
__global__ __launch_bounds__(256)
void k_pre(const float* __restrict__ x, const float* __restrict__ Wemb,
           const float* __restrict__ bemb, const float* __restrict__ Wq,
           const float* __restrict__ Wk, const float* __restrict__ Wv,
           const float* __restrict__ Wout,
           float* __restrict__ Xp, float* __restrict__ cp,
           float* __restrict__ Z0t, float* __restrict__ Z1t,
           float* __restrict__ Y1t, float* __restrict__ F0t,
           float* __restrict__ Et, float* __restrict__ Er,
           float* __restrict__ F0r, float* __restrict__ Z0r,
           float* __restrict__ w1g, int nch) {
  const int bid = blockIdx.x, t = threadIdx.x;
  __shared__ __align__(16) float esT[512];
  __shared__ __align__(16) float fsT[512];
  __shared__ __align__(16) float psT[512];
  __shared__ __align__(16) float4 ppA[4][64];
  __shared__ __align__(16) float4 ppB[4][64];
  __shared__ __align__(16) float xs[2][16][64];
  __shared__ __align__(16) float cs[16][64];

  const int nxtx = BATCH * nch * 2;

  if (bid < 198) {
    // ---------------- chain-row blocks ----------------
    int role, idx;
    if (bid < 66)       { role = 0; idx = bid; }        // Y1 (3 passes)
    else if (bid < 132) { role = 1; idx = bid - 66; }   // Z0
    else                { role = 2; idx = bid - 132; }  // Z1
    const int grp = idx >> 1, half = idx & 1;
    const int r0 = grp * 2;
    const int nr = (r0 + 2 <= 65) ? 2 : 1;
    const int jg = t & 63, ks = t >> 6, j0 = jg * 4;

    {
      const float v0 = (r0 < 64) ? Wemb[(size_t)r0 * DM + t] : bemb[t];
      float v1 = 0.f;
      if (nr == 2) v1 = (r0 + 1 < 64) ? Wemb[(size_t)(r0 + 1) * DM + t] : bemb[t];
      esT[t * 2] = v0; esT[t * 2 + 1] = v1;
    }
    __syncthreads();

    // NT pass: dstT[j][r] = sum_k src[k][r] * M[k][j]; j via float4, k sliced 4x
    auto nt_pass = [&](const float* src, const float* __restrict__ M,
                       float* dstT, bool f0store) {
      float4 A0 = make_float4(0.f, 0.f, 0.f, 0.f);
      float4 A1 = make_float4(0.f, 0.f, 0.f, 0.f);
      const int kbeg = ks * 64;
#pragma unroll 8
      for (int i = 0; i < 64; ++i) {
        const int k = kbeg + i;
        const float4 m =
            *reinterpret_cast<const float4*>(M + (size_t)k * DM + j0);
        const float s0 = src[k * 2], s1 = src[k * 2 + 1];
        A0.x += s0 * m.x; A0.y += s0 * m.y; A0.z += s0 * m.z; A0.w += s0 * m.w;
        A1.x += s1 * m.x; A1.y += s1 * m.y; A1.z += s1 * m.z; A1.w += s1 * m.w;
      }
      ppA[ks][jg] = A0; ppB[ks][jg] = A1;
      __syncthreads();
      if (t < 128) {
        const int rr = t >> 6, jj = t & 63;
        float4 s;
        if (rr == 0) {
          const float4 q0 = ppA[0][jj], q1 = ppA[1][jj];
          const float4 q2 = ppA[2][jj], q3 = ppA[3][jj];
          s = make_float4((q0.x + q1.x) + (q2.x + q3.x),
                          (q0.y + q1.y) + (q2.y + q3.y),
                          (q0.z + q1.z) + (q2.z + q3.z),
                          (q0.w + q1.w) + (q2.w + q3.w));
        } else {
          const float4 q0 = ppB[0][jj], q1 = ppB[1][jj];
          const float4 q2 = ppB[2][jj], q3 = ppB[3][jj];
          s = make_float4((q0.x + q1.x) + (q2.x + q3.x),
                          (q0.y + q1.y) + (q2.y + q3.y),
                          (q0.z + q1.z) + (q2.z + q3.z),
                          (q0.w + q1.w) + (q2.w + q3.w));
        }
        dstT[(jj * 4 + 0) * 2 + rr] = s.x;
        dstT[(jj * 4 + 1) * 2 + rr] = s.y;
        dstT[(jj * 4 + 2) * 2 + rr] = s.z;
        dstT[(jj * 4 + 3) * 2 + rr] = s.w;
        if (f0store && half == 0 && rr < nr) {
          *reinterpret_cast<float4*>(&F0r[(size_t)(r0 + rr) * 256 + jj * 4]) = s;
          F0t[(size_t)(jj * 4 + 0) * DP + r0 + rr] = s.x;
          F0t[(size_t)(jj * 4 + 1) * DP + r0 + rr] = s.y;
          F0t[(size_t)(jj * 4 + 2) * DP + r0 + rr] = s.z;
          F0t[(size_t)(jj * 4 + 3) * DP + r0 + rr] = s.w;
        }
      }
      __syncthreads();
    };

    const float* src2 = esT;
    const float* M1; const float* M2; float* dst; float* dstR = nullptr;
    if (role == 0) {
      nt_pass(esT, Wv, fsT, true);                 // F0 = Ebar @ Wv0
      src2 = fsT;
      M1 = Wq + (size_t)DM * DM; M2 = Wk + (size_t)DM * DM; dst = Y1t;
    } else if (role == 1) {
      M1 = Wq; M2 = Wk; dst = Z0t; dstR = Z0r;
    } else {
      M1 = Wq + (size_t)DM * DM; M2 = Wk + (size_t)DM * DM; dst = Z1t;
    }
    nt_pass(src2, M1, psT, false);

    // TN half pass: dst[j][r] = sum_k p[k][r] * M2[j][k]
    {
      const int j = half * 128 + (t & 127);
      const int r = t >> 7;
      const float4* Mrow = reinterpret_cast<const float4*>(M2 + (size_t)j * DM);
      float a0 = 0.f, a1 = 0.f, a2 = 0.f, a3 = 0.f;
#pragma unroll 4
      for (int u = 0; u < 16; ++u) {
        const float4 m0 = Mrow[u * 4 + 0], m1 = Mrow[u * 4 + 1];
        const float4 m2 = Mrow[u * 4 + 2], m3 = Mrow[u * 4 + 3];
        a0 += m0.x * psT[(u * 16 + 0) * 2 + r] + m0.y * psT[(u * 16 + 1) * 2 + r] +
              m0.z * psT[(u * 16 + 2) * 2 + r] + m0.w * psT[(u * 16 + 3) * 2 + r];
        a1 += m1.x * psT[(u * 16 + 4) * 2 + r] + m1.y * psT[(u * 16 + 5) * 2 + r] +
              m1.z * psT[(u * 16 + 6) * 2 + r] + m1.w * psT[(u * 16 + 7) * 2 + r];
        a2 += m2.x * psT[(u * 16 + 8) * 2 + r] + m2.y * psT[(u * 16 + 9) * 2 + r] +
              m2.z * psT[(u * 16 + 10) * 2 + r] + m2.w * psT[(u * 16 + 11) * 2 + r];
        a3 += m3.x * psT[(u * 16 + 12) * 2 + r] + m3.y * psT[(u * 16 + 13) * 2 + r] +
              m3.z * psT[(u * 16 + 14) * 2 + r] + m3.w * psT[(u * 16 + 15) * 2 + r];
      }
      const float acc = (a0 + a1) + (a2 + a3);
      if (r < nr) {
        dst[(size_t)j * DP + r0 + r] = acc;
        if (dstR) dstR[(size_t)(r0 + r) * 256 + j] = acc;
      }
    }
  } else if (bid < 198 + nxtx) {
    // ---------------- x^T x partials (pipelined, double-buffered) ----------
    const int idx = bid - 198;
    const int per_b = nch * 2;
    const int b = idx / per_b, r5 = idx % per_b, ch = r5 >> 1, half = r5 & 1;
    const int chrows = SEQ / nch;
    const int nstage = chrows / 16;
    const float* xb = x + ((size_t)b * SEQ + (size_t)ch * chrows) * 64;
    const int trs = t >> 4, tcs = t & 15;
    const int tr2 = t >> 3, tc2 = t & 7;

    float acc[2][4] = {{0.f, 0.f, 0.f, 0.f}, {0.f, 0.f, 0.f, 0.f}};
    float4 csum = make_float4(0.f, 0.f, 0.f, 0.f);
    float4 v = *reinterpret_cast<const float4*>(xb + (size_t)trs * 64 + tcs * 4);
    int buf = 0;
    for (int st = 0; st < nstage; ++st) {
      *reinterpret_cast<float4*>(&xs[buf][trs][tcs * 4]) = v;
      csum.x += v.x; csum.y += v.y; csum.z += v.z; csum.w += v.w;
      __syncthreads();
      float4 vn = make_float4(0.f, 0.f, 0.f, 0.f);
      if (st + 1 < nstage)
        vn = *reinterpret_cast<const float4*>(
            xb + (size_t)((st + 1) * 16 + trs) * 64 + tcs * 4);
#pragma unroll
      for (int s = 0; s < 16; ++s) {
        const float a0 = xs[buf][s][tr2 * 2 + 0];
        const float a1 = xs[buf][s][tr2 * 2 + 1];
        const float4 b4 =
            *reinterpret_cast<const float4*>(&xs[buf][s][half * 32 + tc2 * 4]);
        acc[0][0] += a0 * b4.x; acc[0][1] += a0 * b4.y;
        acc[0][2] += a0 * b4.z; acc[0][3] += a0 * b4.w;
        acc[1][0] += a1 * b4.x; acc[1][1] += a1 * b4.y;
        acc[1][2] += a1 * b4.z; acc[1][3] += a1 * b4.w;
      }
      v = vn; buf ^= 1;
    }
    float* Xpb = Xp + (size_t)(b * nch + ch) * 4096;
#pragma unroll
    for (int rr = 0; rr < 2; ++rr) {
      const float4 s4 =
          make_float4(acc[rr][0], acc[rr][1], acc[rr][2], acc[rr][3]);
      *reinterpret_cast<float4*>(
          &Xpb[(size_t)(tr2 * 2 + rr) * 64 + half * 32 + tc2 * 4]) = s4;
    }
    if (half == 0) {
      *reinterpret_cast<float4*>(&cs[trs][tcs * 4]) = csum;
      __syncthreads();
      if (t < 64) {
        float s = 0.f;
#pragma unroll
        for (int g = 0; g < 16; ++g) s += cs[g][t];
        cp[(size_t)(b * nch + ch) * 64 + t] = s;
      }
    }
  } else if (bid == 198 + nxtx) {
    // ---------------- Et / Er build + pad zeroing ----------------
    for (int i = 0; i < 64; ++i) {
      const float w = Wemb[(size_t)i * DM + t];
      Et[(size_t)t * DP + i] = w;
      Er[(size_t)i * 256 + t] = w;
    }
    Et[(size_t)t * DP + 64] = bemb[t];
    Er[(size_t)64 * 256 + t] = bemb[t];
    for (int i = 65; i < DP; ++i) {
      Et[(size_t)t * DP + i] = 0.f;
      Er[(size_t)i * 256 + t] = 0.f;
      F0r[(size_t)i * 256 + t] = 0.f;
      Z0r[(size_t)i * 256 + t] = 0.f;
    }
  } else {
    // ---------------- w1 = Wv1 @ Wout ----------------
    esT[t] = Wout[t];
    __syncthreads();
    const float* Wv1 = Wv + (size_t)DM * DM;
    w1g[t] = rowdot256(Wv1 + (size_t)t * DM, esT);
  }
}

// ---------------------------------------------------------------------------
// Kernel 2 (4 blocks x 1024): per-batch chain in 65/80-dim space.
//   out = cbar.e_o + a*(g.f0) + a*(pv.Xq) + bout
// ---------------------------------------------------------------------------
__global__ __launch_bounds__(1024)
void k_post(const float* __restrict__ Xp, const float* __restrict__ cp,
            const float* __restrict__ Et, const float* __restrict__ Er,
            const float* __restrict__ F0r, const float* __restrict__ Z0t,
            const float* __restrict__ Z0r, const float* __restrict__ Z1t,
            const float* __restrict__ Y1t, const float* __restrict__ Wout,
            const float* __restrict__ bout, const float* __restrict__ w1g,
            float* __restrict__ out, int nch) {
  const int b = blockIdx.x, t = threadIdx.x;
  __shared__ __align__(16) float X[DP][81];
  __shared__ __align__(16) float cl[DP], eo[DP], e1[DP], f0[DP], f1[DP];
  __shared__ __align__(16) float al[256], hv[256], z2[256], t2[256];
  __shared__ __align__(16) float cM0[DP], y[DP], g[DP], qv[DP];
  __shared__ __align__(16) float rE[DP], rF[DP], t1[DP], Xq[DP];
  __shared__ __align__(16) float pr0[DP], pr1[DP], pr2[DP];
  __shared__ float dots[3];

  // ---- P1: Xbar reduce / cbar / e,f vectors / pad zeroing
  if (t < 512) {
    const int e = t * 8;
    float4 aA = make_float4(0.f, 0.f, 0.f, 0.f);
    float4 aB = make_float4(0.f, 0.f, 0.f, 0.f);
#pragma unroll 4
    for (int ch = 0; ch < nch; ++ch) {
      const float* P = Xp + (size_t)(b * nch + ch) * 4096 + e;
      const float4 p1 = *reinterpret_cast<const float4*>(P);
      const float4 p2 = *reinterpret_cast<const float4*>(P + 4);
      aA.x += p1.x; aA.y += p1.y; aA.z += p1.z; aA.w += p1.w;
      aB.x += p2.x; aB.y += p2.y; aB.z += p2.z; aB.w += p2.w;
    }
    const int r = e >> 6, c = e & 63;
    X[r][c + 0] = aA.x; X[r][c + 1] = aA.y; X[r][c + 2] = aA.z; X[r][c + 3] = aA.w;
    X[r][c + 4] = aB.x; X[r][c + 5] = aB.y; X[r][c + 6] = aB.z; X[r][c + 7] = aB.w;
  } else if (t < 576) {
    const int i = t - 512;
    float s = 0.f;
#pragma unroll 4
    for (int ch = 0; ch < nch; ++ch) s += cp[(size_t)(b * nch + ch) * 64 + i];
    cl[i] = s;
    if (i == 0) cl[64] = (float)SEQ;
    if (i == 1) for (int p = 65; p < DP; ++p) cl[p] = 0.f;
  } else if (t < 896) {
    const int u = t - 576, grp = u / DP, i = u - grp * DP;
    const float* Mr = (grp < 2) ? Er : F0r;
    const float* vv = (grp & 1) ? w1g : Wout;
    const float r = rowdot256(Mr + (size_t)i * 256, vv);
    if (grp == 0) eo[i] = r;
    else if (grp == 1) e1[i] = r;
    else if (grp == 2) f0[i] = r;
    else f1[i] = r;
  } else {
    for (int n = t - 896; n < 2304; n += 128) {
      if (n < 1280) X[n >> 4][64 + (n & 15)] = 0.f;
      else { const int m = n - 1280; X[64 + (m >> 6)][m & 63] = 0.f; }
    }
  }
  __syncthreads();

  // ---- P2: finish Xbar (c row/col); al = cbar @ Z0
  if (t < 64) { X[t][64] = cl[t]; X[64][t] = cl[t]; }
  else if (t == 64) X[64][64] = (float)SEQ;
  else if (t >= 128 && t < 384)
    al[t - 128] = rowdot65(Z0t + (size_t)(t - 128) * DP, cl);
  __syncthreads();

  // ---- S2: cM0 = al Ebar^T ; y = Xbar f1
  if (t < 80) cM0[t] = rowdot256(Er + (size_t)t * 256, al);
  else if (t >= 128 && t < 208) {
    const int i = t - 128; float s = 0.f;
    for (int j = 0; j < DP; ++j) s += X[i][j] * f1[j];
    y[i] = s;
  }
  __syncthreads();

  // ---- S3: g = cM0 Xbar ; z2 = y Ebar
  if (t < 80) {
    float s = 0.f;
    for (int i = 0; i < DP; ++i) s += cM0[i] * X[i][t];
    g[t] = s;
  } else if (t >= 128 && t < 384)
    z2[t - 128] = rowdot65(Et + (size_t)(t - 128) * DP, y);
  __syncthreads();

  // ---- S4: hv = cbar Z1 + a*(g Y1) ; qv = e1 + a*(z2 Z0^T)
  if (t < 256)
    hv[t] = rowdot65(Z1t + (size_t)t * DP, cl) +
            ALPHA * rowdot65(Y1t + (size_t)t * DP, g);
  else if (t < 336) {
    const int i = t - 256;
    qv[i] = e1[i] + ALPHA * rowdot256(Z0r + (size_t)i * 256, z2);
  }
  __syncthreads();

  // ---- S5: rE = hv Ebar^T ; rF = hv F0^T ; Xq = Xbar qv
  if (t < 80) rE[t] = rowdot256(Er + (size_t)t * 256, hv);
  else if (t >= 128 && t < 208)
    rF[t - 128] = rowdot256(F0r + (size_t)(t - 128) * 256, hv);
  else if (t >= 256 && t < 336) {
    const int i = t - 256; float s = 0.f;
    for (int j = 0; j < DP; ++j) s += X[i][j] * qv[j];
    Xq[i] = s;
  }
  __syncthreads();

  // ---- S6: t1 = rF Xbar
  if (t < 80) {
    float s = 0.f;
    for (int i = 0; i < DP; ++i) s += rF[i] * X[i][t];
    t1[t] = s;
  }
  __syncthreads();

  // ---- S7: t2 = t1 Ebar
  if (t < 256) t2[t] = rowdot65(Et + (size_t)t * DP, t1);
  __syncthreads();

  // ---- S8: pv = rE + a*(t2 Z0^T); products
  if (t < 80) {
    const float zv = rowdot256(Z0r + (size_t)t * 256, t2);
    pr2[t] = (rE[t] + ALPHA * zv) * Xq[t];
  } else if (t >= 128 && t < 208) {
    const int i = t - 128; pr0[i] = cl[i] * eo[i];
  } else if (t >= 256 && t < 336) {
    const int i = t - 256; pr1[i] = g[i] * f0[i];
  }
  __syncthreads();

  // ---- S9: reduce 3 dots
  const int w = t >> 6, l = t & 63;
  if (w < 3) {
    const float* pr = (w == 0) ? pr0 : (w == 1) ? pr1 : pr2;
    float v = pr[l] + ((l < 16) ? pr[64 + l] : 0.f);
    v = wave_red(v);
    if (l == 0) dots[w] = v;
  }
  __syncthreads();
  if (t == 0) out[b] = dots[0] + ALPHA * dots[1] + ALPHA * dots[2] + bout[0];
}

}  // namespace

extern "C" void kernel_launch(void* const* d_in, const int* in_sizes, int n_in,
                              void* d_out, int out_size, void* d_ws, size_t ws_size,
                              hipStream_t stream) {
  const float* x    = (const float*)d_in[0];
  const float* Wemb = (const float*)d_in[1];
  const float* bemb = (const float*)d_in[2];
  const float* Wq   = (const float*)d_in[3];
  const float* Wk   = (const float*)d_in[4];
  const float* Wv   = (const float*)d_in[5];
  const float* Wout = (const float*)d_in[6];
  const float* bout = (const float*)d_in[7];
  float* out = (float*)d_out;

  const size_t fixed = (size_t)5 * 256 * DP + (size_t)3 * DP * 256 + 256;
  int nch = 16;
  while (nch > 2 &&
         ((size_t)BATCH * nch * (4096 + 64) + fixed) * sizeof(float) > ws_size)
    nch >>= 1;

  float* p = (float*)d_ws;
  float* Xp  = p; p += (size_t)BATCH * nch * 4096;
  float* cp  = p; p += (size_t)BATCH * nch * 64;
  float* Z0t = p; p += 256 * DP;
  float* Z1t = p; p += 256 * DP;
  float* Y1t = p; p += 256 * DP;
  float* F0t = p; p += 256 * DP;
  float* Et  = p; p += 256 * DP;
  float* Er  = p; p += DP * 256;
  float* F0r = p; p += DP * 256;
  float* Z0r = p; p += DP * 256;
  float* w1g = p; p += 256;

  const int nblk = 198 + BATCH * nch * 2 + 2;
  k_pre<<<nblk, 256, 0, stream>>>(x, Wemb, bemb, Wq, Wk, Wv, Wout,
                                  Xp, cp, Z0t, Z1t, Y1t, F0t, Et, Er, F0r, Z0r,
                                  w1g, nch);
  k_post<<<BATCH, 1024, 0, stream>>>(Xp, cp, Et, Er, F0r, Z0t, Z0r, Z1t, Y1t,
                                     Wout, bout, w1g, out, nch);
}